// Round 2
// baseline (97.532 us; speedup 1.0000x reference)
//
#include <hip/hip_runtime.h>

// SparseLookupTable via one-hot MFMA (conventions HW-verified in prev round):
//   out[b,o] = sum_k lut[inp[b,k], wgt[o,k]],  B=512, O=1024, K=128, LUT 256x256.
//   A_k[b, j] = lut[inp[b,k], j]   (f16 rows gathered from LDS, ds_read_b128)
//   B_k[j, o] = onehot(wgt[o,k])   (built in VALU registers)
// MFMA f32_16x16x32_f16, 8 K-steps of 32 cover the 256-wide one-hot dim.
//
// This round: re-decomposed to kill register spills.
//   wave = (mt, kg): 2 M-tiles x 8 K-groups; each wave: 16 rows x 64 cols x 16 kslices.
//   acc 32->16 VGPRs, single A-stream, s-major LUT layout so all 8 A-reads per
//   kslice share one base VGPR (+ compile-time s*16384 displacement) and spread
//   over 8 LDS bank groups. K-reduction over kg-waves in dead LUT LDS.

#define KDIM 128

typedef _Float16 f16x8 __attribute__((ext_vector_type(8)));
typedef float    f32x4 __attribute__((ext_vector_type(4)));

union F16Frag { uint4 u; f16x8 h; };

__global__ __launch_bounds__(1024, 4)
void slt_mfma(const int* __restrict__ inp, const int* __restrict__ wgt,
              const float* __restrict__ lut, float* __restrict__ out)
{
    // 131072 (LUT f16, s-major swizzled) + 8192 (i_lds [128][32] u16)
    // + 16384 (w_lds [128][64] u16) = 155648 B
    __shared__ __attribute__((aligned(16))) unsigned char smem[155648];
    unsigned char*  lutB  = smem;
    unsigned short* i_lds = (unsigned short*)(smem + 131072);
    unsigned short* w_lds = (unsigned short*)(smem + 139264);

    const int tid   = threadIdx.x;
    const int otile = blockIdx.x;   // 16 tiles of 64 outputs
    const int btile = blockIdx.y;   // 16 tiles of 32 batch rows

    // ---- stage LUT fp32 -> fp16, s-major swizzled ----
    // logical (row r, byte lb in 512B row) -> phys = (lb>>6)*16384 + r*64
    //                                              + ((lb&63) ^ ((r&3)<<4))
    // XOR touches bits 4-5 only: 8B/16B alignment preserved, bijective per chunk.
    {
        const float4* lut4 = (const float4*)lut;
        #pragma unroll
        for (int it = 0; it < 16; ++it) {
            int idx = it * 1024 + tid;          // coalesced; wave covers one row
            float4 v = lut4[idx];
            union { _Float16 h[4]; unsigned long long u; } pk;
            pk.h[0] = (_Float16)v.x; pk.h[1] = (_Float16)v.y;
            pk.h[2] = (_Float16)v.z; pk.h[3] = (_Float16)v.w;
            unsigned r  = (unsigned)idx >> 6;           // LUT row
            unsigned lb = ((unsigned)idx & 63u) << 3;   // logical byte in row
            unsigned off = ((lb >> 6) << 14) + (r << 6)
                         + ((lb & 63u) ^ ((r & 3u) << 4));
            *(unsigned long long*)(lutB + off) = pk.u;
        }
    }

    // ---- stage indices transposed, u16: i_lds[k][b], w_lds[k][o] ----
    {
        int b = tid >> 5, kg = tid & 31;
        int4 iv = *(const int4*)(inp + (size_t)(btile * 32 + b) * KDIM + kg * 4);
        i_lds[(kg*4+0)*32 + b] = (unsigned short)(iv.x & 255);
        i_lds[(kg*4+1)*32 + b] = (unsigned short)(iv.y & 255);
        i_lds[(kg*4+2)*32 + b] = (unsigned short)(iv.z & 255);
        i_lds[(kg*4+3)*32 + b] = (unsigned short)(iv.w & 255);
    }
    #pragma unroll
    for (int s2 = 0; s2 < 2; ++s2) {
        int t2 = tid + s2 * 1024;
        int o = t2 >> 5, kg = t2 & 31;
        int4 wv4 = *(const int4*)(wgt + (size_t)(otile * 64 + o) * KDIM + kg * 4);
        w_lds[(kg*4+0)*64 + o] = (unsigned short)(wv4.x & 255);
        w_lds[(kg*4+1)*64 + o] = (unsigned short)(wv4.y & 255);
        w_lds[(kg*4+2)*64 + o] = (unsigned short)(wv4.z & 255);
        w_lds[(kg*4+3)*64 + o] = (unsigned short)(wv4.w & 255);
    }
    __syncthreads();

    const int      lane = tid & 63;
    const int      wid  = tid >> 6;
    const int      mt   = wid & 1;          // M-tile (16 rows) owned by this wave
    const int      kg   = wid >> 1;         // k-group: kslices kg*16 .. kg*16+15
    const unsigned colq = (unsigned)(lane & 15);               // A row / B col
    const unsigned h8   = ((unsigned)((lane >> 4) & 3)) << 3;  // k-subgroup * 8
    const unsigned h16  = h8 << 1;                             // byte offset

    f32x4 acc[4];
    #pragma unroll
    for (int nt = 0; nt < 4; ++nt) { f32x4 z = {0.f,0.f,0.f,0.f}; acc[nt] = z; }

    unsigned r_next = i_lds[(kg * 16) * 32 + mt * 16 + colq];

    #pragma unroll 1
    for (int j = 0; j < 16; ++j) {
        const int ks = kg * 16 + j;
        const unsigned r0 = r_next;
        r_next = i_lds[(((ks + 1) & 127) * 32) + mt * 16 + colq];   // prefetch
        const unsigned char* pA =
            lutB + ((r0 << 6) + (h16 ^ ((r0 & 3u) << 4)));

        // One-hot prep per N-tile: hot element pre-placed into p[nt][0..3],
        // live only at s-step sl[nt]. (Verbatim from HW-verified round.)
        unsigned p[4][4]; unsigned sl[4];
        #pragma unroll
        for (int nt = 0; nt < 4; ++nt) {
            unsigned wv   = w_lds[ks * 64 + nt * 16 + colq];
            unsigned u    = wv - h8;
            unsigned slot = u & 7u;
            unsigned long long pk = 0x3C00ULL << ((slot & 3u) << 4);
            unsigned lo = (unsigned)pk, hi = (unsigned)(pk >> 32);
            unsigned lh    = (slot < 4u);
            unsigned valid = ((u & 31u) < 8u);
            sl[nt] = valid ? (u >> 5) : 0xFFu;
            p[nt][0] = lh ? lo : 0u;
            p[nt][1] = lh ? hi : 0u;
            p[nt][2] = lh ? 0u : lo;
            p[nt][3] = lh ? 0u : hi;
        }

        // 8 MFMA K-steps; A-read base + compile-time s*16384 displacement
        #pragma unroll
        for (int s = 0; s < 8; ++s) {
            F16Frag a0;
            a0.u = *(const uint4*)(pA + ((unsigned)s << 14));
            #pragma unroll
            for (int nt = 0; nt < 4; ++nt) {
                F16Frag bb;
                bool take = (sl[nt] == (unsigned)s);
                bb.u.x = take ? p[nt][0] : 0u;
                bb.u.y = take ? p[nt][1] : 0u;
                bb.u.z = take ? p[nt][2] : 0u;
                bb.u.w = take ? p[nt][3] : 0u;
                acc[nt] = __builtin_amdgcn_mfma_f32_16x16x32_f16(a0.h, bb.h, acc[nt], 0, 0, 0);
            }
        }
    }

    // ---- cross-wave K-reduction in dead LUT LDS (64 KB) + store ----
    __syncthreads();                      // all waves done reading lutB
    f32x4* red = (f32x4*)smem;            // [wid][nt][lane] : 16*4*64 f32x4
    #pragma unroll
    for (int nt = 0; nt < 4; ++nt)
        red[wid * 256 + nt * 64 + lane] = acc[nt];
    __syncthreads();

    if (wid < 8) {
        const int mt2 = wid >> 2;         // 0..1
        const int nt2 = wid & 3;          // 0..3
        f32x4 s4 = {0.f, 0.f, 0.f, 0.f};
        #pragma unroll
        for (int g = 0; g < 8; ++g)       // sum over kg-waves (wid = kg*2+mt)
            s4 += red[(g * 2 + mt2) * 256 + nt2 * 64 + lane];
        // D layout: col = lane&15, row = (lane>>4)*4 + reg  (HW-verified)
        const int rrow = btile * 32 + mt2 * 16 + ((lane >> 4) & 3) * 4;
        const int ccol = otile * 64 + nt2 * 16 + (lane & 15);
        #pragma unroll
        for (int c = 0; c < 4; ++c)
            out[(size_t)(rrow + c) * 1024 + ccol] = s4[c];
    }
}

extern "C" void kernel_launch(void* const* d_in, const int* in_sizes, int n_in,
                              void* d_out, int out_size, void* d_ws, size_t ws_size,
                              hipStream_t stream) {
    const int*   inp = (const int*)d_in[0];    // (512, 32, 4) int32
    const int*   wgt = (const int*)d_in[1];    // (1024, 32, 4) int32
    const float* lut = (const float*)d_in[2];  // (256, 256) fp32
    float*       out = (float*)d_out;          // (512, 1024) fp32

    dim3 grid(16, 16);
    dim3 block(1024);
    slt_mfma<<<grid, block, 0, stream>>>(inp, wgt, lut, out);
}

// Round 3
// 87.465 us; speedup vs baseline: 1.1151x; 1.1151x over previous
//
#include <hip/hip_runtime.h>

// SparseLookupTable via one-hot MFMA (data conventions HW-verified rounds 1-2):
//   out[b,o] = sum_k lut[inp[b,k], wgt[o,k]],  B=512, O=1024, K=128, LUT 256x256.
//   A_k[b, j] = lut[inp[b,k], j]   (f16 rows gathered from LDS, ds_read_b128)
//   B_k[j, o] = onehot(wgt[o,k])   (built in VALU registers)
// MFMA f32_16x16x32_f16, 8 K-steps of 32 cover the 256-wide one-hot dim.
//
// Round-3 fixes (from measured counters: 36.4K conflict-cyc/block, VALU 59%):
//  1. wave = kg (full 32x64 tile, 8 kslices): bb shared across both M-tiles
//     -> B-select VALU per CU halves (2.5 VALU per MFMA).
//  2. full-entropy XOR swizzle: phys = r*512 + (s>>1)*128 + ((4(s&1)+q)^(r&7))*16.
//     16 gather-lanes/quarter spread over 8 bank groups (was 4); per (kslice,mt)
//     addressing = 2 base VGPRs + compile-time immediates (zero per-s VALU).
//  3. one-pass b128 reduction epilogue in the dead LUT region.

#define KDIM 128

typedef _Float16 f16x8 __attribute__((ext_vector_type(8)));
typedef float    f32x4 __attribute__((ext_vector_type(4)));

union F16Frag { uint4 u; f16x8 h; };

__global__ __launch_bounds__(1024, 4)
void slt_mfma(const int* __restrict__ inp, const int* __restrict__ wgt,
              const float* __restrict__ lut, float* __restrict__ out)
{
    // 131072 (LUT f16 swizzled) + 8192 (i_lds [128][32] u16)
    // + 16384 (w_lds [128][64] u16) = 155648 B
    __shared__ __attribute__((aligned(16))) unsigned char smem[155648];
    unsigned char*  lutB  = smem;
    unsigned short* i_lds = (unsigned short*)(smem + 131072);
    unsigned short* w_lds = (unsigned short*)(smem + 139264);

    const int tid   = threadIdx.x;
    const int otile = blockIdx.x;   // 16 tiles of 64 outputs
    const int btile = blockIdx.y;   // 16 tiles of 32 batch rows

    // ---- stage LUT fp32 -> fp16, chunk-XOR swizzled ----
    // row r, logical byte lb (512/row). chunk = lb>>4 (16B units, 0..31).
    // phys = r*512 + (((chunk&24) | ((chunk ^ (r&7)) & 7)) << 4) + (lb & 15)
    {
        const float4* lut4 = (const float4*)lut;
        #pragma unroll
        for (int it = 0; it < 16; ++it) {
            int idx = it * 1024 + tid;          // f32x4 group; coalesced
            float4 v = lut4[idx];
            union { _Float16 h[4]; unsigned long long u; } pk;
            pk.h[0] = (_Float16)v.x; pk.h[1] = (_Float16)v.y;
            pk.h[2] = (_Float16)v.z; pk.h[3] = (_Float16)v.w;
            unsigned r  = (unsigned)idx >> 6;           // LUT row
            unsigned lb = ((unsigned)idx & 63u) << 3;   // logical byte in row
            unsigned ch = lb >> 4;
            unsigned sw = (ch & 24u) | ((ch ^ (r & 7u)) & 7u);
            unsigned off = (r << 9) + (sw << 4) + (lb & 15u);
            *(unsigned long long*)(lutB + off) = pk.u;
        }
    }

    // ---- stage indices transposed, u16: i_lds[k][b], w_lds[k][o] ----
    {
        int b = tid >> 5, kg = tid & 31;
        int4 iv = *(const int4*)(inp + (size_t)(btile * 32 + b) * KDIM + kg * 4);
        i_lds[(kg*4+0)*32 + b] = (unsigned short)(iv.x & 255);
        i_lds[(kg*4+1)*32 + b] = (unsigned short)(iv.y & 255);
        i_lds[(kg*4+2)*32 + b] = (unsigned short)(iv.z & 255);
        i_lds[(kg*4+3)*32 + b] = (unsigned short)(iv.w & 255);
    }
    #pragma unroll
    for (int s2 = 0; s2 < 2; ++s2) {
        int t2 = tid + s2 * 1024;
        int o = t2 >> 5, kg = t2 & 31;
        int4 wv4 = *(const int4*)(wgt + (size_t)(otile * 64 + o) * KDIM + kg * 4);
        w_lds[(kg*4+0)*64 + o] = (unsigned short)(wv4.x & 255);
        w_lds[(kg*4+1)*64 + o] = (unsigned short)(wv4.y & 255);
        w_lds[(kg*4+2)*64 + o] = (unsigned short)(wv4.z & 255);
        w_lds[(kg*4+3)*64 + o] = (unsigned short)(wv4.w & 255);
    }
    __syncthreads();

    const int      lane = tid & 63;
    const int      wid  = tid >> 6;                 // kg: kslices wid*8..wid*8+7
    const unsigned colq = (unsigned)(lane & 15);    // A row-lane / B col
    const unsigned q    = (unsigned)((lane >> 4) & 3);
    const unsigned h8   = q << 3;                   // k-subgroup * 8

    f32x4 acc[2][4];
    #pragma unroll
    for (int a = 0; a < 2; ++a)
        #pragma unroll
        for (int n = 0; n < 4; ++n) { f32x4 z = {0.f,0.f,0.f,0.f}; acc[a][n] = z; }

    #pragma unroll 1
    for (int j = 0; j < 8; ++j) {
        const int ks = wid * 8 + j;

        // A rows for both 16-row M-tiles
        unsigned r0 = i_lds[ks * 32 + colq];
        unsigned r1 = i_lds[ks * 32 + 16 + colq];
        // base (even s) and base^4-group (odd s); offsets (s>>1)*128 are imms
        unsigned L0 = q ^ (r0 & 7u), L1 = q ^ (r1 & 7u);
        const unsigned char* pA0 = lutB + ((r0 << 9) + (L0 << 4));
        const unsigned char* pA1 = lutB + ((r1 << 9) + (L1 << 4));
        const unsigned char* pA0o = pA0 + 64u - ((L0 & 4u) << 5);
        const unsigned char* pA1o = pA1 + 64u - ((L1 & 4u) << 5);

        // One-hot prep per N-tile (verbatim from HW-verified rounds)
        unsigned p[4][4]; unsigned sl[4];
        #pragma unroll
        for (int nt = 0; nt < 4; ++nt) {
            unsigned wv   = w_lds[ks * 64 + nt * 16 + colq];
            unsigned u    = wv - h8;
            unsigned slot = u & 7u;
            unsigned long long pk = 0x3C00ULL << ((slot & 3u) << 4);
            unsigned lo = (unsigned)pk, hi = (unsigned)(pk >> 32);
            unsigned lh    = (slot < 4u);
            unsigned valid = ((u & 31u) < 8u);
            sl[nt] = valid ? (u >> 5) : 0xFFu;
            p[nt][0] = lh ? lo : 0u;
            p[nt][1] = lh ? hi : 0u;
            p[nt][2] = lh ? 0u : lo;
            p[nt][3] = lh ? 0u : hi;
        }

        // 8 MFMA K-steps; each bb feeds BOTH M-tiles (shared B-construction)
        #pragma unroll
        for (int s = 0; s < 8; ++s) {
            const unsigned disp = (unsigned)(s >> 1) * 128u;
            F16Frag a0, a1;
            a0.u = *(const uint4*)(((s & 1) ? pA0o : pA0) + disp);
            a1.u = *(const uint4*)(((s & 1) ? pA1o : pA1) + disp);
            #pragma unroll
            for (int nt = 0; nt < 4; ++nt) {
                F16Frag bb;
                bool take = (sl[nt] == (unsigned)s);
                bb.u.x = take ? p[nt][0] : 0u;
                bb.u.y = take ? p[nt][1] : 0u;
                bb.u.z = take ? p[nt][2] : 0u;
                bb.u.w = take ? p[nt][3] : 0u;
                acc[0][nt] = __builtin_amdgcn_mfma_f32_16x16x32_f16(a0.h, bb.h, acc[0][nt], 0, 0, 0);
                acc[1][nt] = __builtin_amdgcn_mfma_f32_16x16x32_f16(a1.h, bb.h, acc[1][nt], 0, 0, 0);
            }
        }
    }

    // ---- one-pass cross-wave K-reduction in dead LUT LDS (128 KB) ----
    __syncthreads();                      // all waves done reading lutB
    f32x4* red = (f32x4*)smem;            // [wid][mt][nt][lane]
    #pragma unroll
    for (int mt = 0; mt < 2; ++mt)
        #pragma unroll
        for (int nt = 0; nt < 4; ++nt)
            red[((wid * 2 + mt) * 4 + nt) * 64 + lane] = acc[mt][nt];
    __syncthreads();

    if (tid < 512) {
        const int mt2 = tid >> 8;         // 0..1
        const int nt2 = (tid >> 6) & 3;   // 0..3
        const int ln  = tid & 63;
        f32x4 s4 = {0.f, 0.f, 0.f, 0.f};
        #pragma unroll
        for (int w = 0; w < 16; ++w)
            s4 += red[((w * 2 + mt2) * 4 + nt2) * 64 + ln];
        // D layout: col = lane&15, row = (lane>>4)*4 + reg  (HW-verified)
        const int rrow = btile * 32 + mt2 * 16 + ((ln >> 4) & 3) * 4;
        const int ccol = otile * 64 + nt2 * 16 + (ln & 15);
        #pragma unroll
        for (int c = 0; c < 4; ++c)
            out[(size_t)(rrow + c) * 1024 + ccol] = s4[c];
    }
}

extern "C" void kernel_launch(void* const* d_in, const int* in_sizes, int n_in,
                              void* d_out, int out_size, void* d_ws, size_t ws_size,
                              hipStream_t stream) {
    const int*   inp = (const int*)d_in[0];    // (512, 32, 4) int32
    const int*   wgt = (const int*)d_in[1];    // (1024, 32, 4) int32
    const float* lut = (const float*)d_in[2];  // (256, 256) fp32
    float*       out = (float*)d_out;          // (512, 1024) fp32

    dim3 grid(16, 16);
    dim3 block(1024);
    slt_mfma<<<grid, block, 0, stream>>>(inp, wgt, lut, out);
}